// Round 4
// baseline (670.046 us; speedup 1.0000x reference)
//
#include <hip/hip_runtime.h>
#include <hip/hip_bf16.h>

#define NUM_ENT   30000
#define NUM_ATTR  10000
#define NUM_TYPES 10
#define HIDDEN    200
#define KPAD      224      // HIDDEN padded to 7*32 for MFMA K-tiles
#define NPAD      30080    // NUM_ENT padded to 235*128
#define N_EDGES   600000
#define BATCH     4096
#define XDIM      401      // 2*HIDDEN + 1
#define RRELU_SLOPE 0.22916666666666666f

using bf16x8 = __attribute__((ext_vector_type(8))) short;
using f32x4  = __attribute__((ext_vector_type(4))) float;
typedef __hip_bfloat16 bf16;

// ---------------------------------------------------------------------------
// Zero an int array (histogram counters).
// ---------------------------------------------------------------------------
__global__ void k_zero_i(int* __restrict__ p, int n) {
    int i = blockIdx.x * blockDim.x + threadIdx.x;
    if (i < n) p[i] = 0;
}

// ---------------------------------------------------------------------------
// Histogram of edge destinations (dst < NUM_ENT only).
// ---------------------------------------------------------------------------
__global__ void k_hist(const int* __restrict__ edst, int* __restrict__ counts) {
    int e = blockIdx.x * blockDim.x + threadIdx.x;
    if (e < N_EDGES) {
        int d = edst[e];
        if (d < NUM_ENT) atomicAdd(&counts[d], 1);
    }
}

// ---------------------------------------------------------------------------
// Exclusive prefix sum over 30000 counts -> offsets[0..NUM_ENT], cursor copy.
// ---------------------------------------------------------------------------
__global__ __launch_bounds__(1024) void k_scan(const int* __restrict__ counts,
                                               int* __restrict__ offsets,
                                               int* __restrict__ cursor) {
    __shared__ int part[1024];
    int t = threadIdx.x;
    const int CH = (NUM_ENT + 1023) / 1024;     // 30
    int base = t * CH;
    int s = 0;
    for (int i = 0; i < CH; ++i) {
        int idx = base + i;
        if (idx < NUM_ENT) s += counts[idx];
    }
    part[t] = s;
    __syncthreads();
    for (int off = 1; off < 1024; off <<= 1) {
        int v = (t >= off) ? part[t - off] : 0;
        __syncthreads();
        part[t] += v;
        __syncthreads();
    }
    int run = (t == 0) ? 0 : part[t - 1];
    for (int i = 0; i < CH; ++i) {
        int idx = base + i;
        if (idx < NUM_ENT) {
            offsets[idx] = run;
            cursor[idx]  = run;
            run += counts[idx];
        }
    }
    if (t == 1023) offsets[NUM_ENT] = part[1023];
}

// ---------------------------------------------------------------------------
// Bucket edge ids by destination node.
// ---------------------------------------------------------------------------
__global__ void k_place(const int* __restrict__ edst, int* __restrict__ cursor,
                        int* __restrict__ sorted) {
    int e = blockIdx.x * blockDim.x + threadIdx.x;
    if (e < N_EDGES) {
        int d = edst[e];
        if (d < NUM_ENT) {
            int p = atomicAdd(&cursor[d], 1);
            sorted[p] = e;
        }
    }
}

// ---------------------------------------------------------------------------
// One wave per node. rgcn_weight staged in LDS (8 KB); edge loop unrolled x4
// with 4 independent accumulators so 4 gathers are in flight at once.
// Writes agg (f32) and the bf16 S row (rrelu*norm, zero-padded). No atomics.
// ---------------------------------------------------------------------------
__global__ void k_aggregate(const float* __restrict__ ent, const float* __restrict__ attr,
                            const float* __restrict__ w, const int* __restrict__ esrc,
                            const int* __restrict__ etype, const int* __restrict__ offsets,
                            const int* __restrict__ sorted, const float* __restrict__ norm,
                            float* __restrict__ agg, bf16* __restrict__ S) {
    __shared__ float wl[NUM_TYPES * HIDDEN];    // 8 KB
    for (int i = threadIdx.x; i < NUM_TYPES * HIDDEN; i += blockDim.x)
        wl[i] = w[i];
    __syncthreads();

    int n    = (blockIdx.x * blockDim.x + threadIdx.x) >> 6;
    int lane = threadIdx.x & 63;
    if (n >= NPAD) return;

    if (n >= NUM_ENT) {                         // S zero-pad rows
        if (lane < KPAD / 4) {
            bf16 z4[4] = {};
            *reinterpret_cast<uint2*>(S + (size_t)n * KPAD + lane * 4) =
                *reinterpret_cast<uint2*>(z4);
        }
        return;
    }

    int beg = offsets[n], end = offsets[n + 1];
    bool act = lane < 50;
    int  c   = lane * 4;

    float4 a0 = make_float4(0, 0, 0, 0), a1 = a0, a2 = a0, a3 = a0;
    int e = beg;
    for (; e + 4 <= end; e += 4) {
        int e0 = sorted[e + 0], e1 = sorted[e + 1], e2 = sorted[e + 2], e3 = sorted[e + 3];
        int s0 = esrc[e0], s1 = esrc[e1], s2 = esrc[e2], s3 = esrc[e3];
        int t0 = etype[e0], t1 = etype[e1], t2 = etype[e2], t3 = etype[e3];
        if (act) {
            const float* p0 = (s0 < NUM_ENT) ? ent + (size_t)s0 * HIDDEN : attr + (size_t)(s0 - NUM_ENT) * HIDDEN;
            const float* p1 = (s1 < NUM_ENT) ? ent + (size_t)s1 * HIDDEN : attr + (size_t)(s1 - NUM_ENT) * HIDDEN;
            const float* p2 = (s2 < NUM_ENT) ? ent + (size_t)s2 * HIDDEN : attr + (size_t)(s2 - NUM_ENT) * HIDDEN;
            const float* p3 = (s3 < NUM_ENT) ? ent + (size_t)s3 * HIDDEN : attr + (size_t)(s3 - NUM_ENT) * HIDDEN;
            float4 h0 = *reinterpret_cast<const float4*>(p0 + c);
            float4 h1 = *reinterpret_cast<const float4*>(p1 + c);
            float4 h2 = *reinterpret_cast<const float4*>(p2 + c);
            float4 h3 = *reinterpret_cast<const float4*>(p3 + c);
            float4 w0 = *reinterpret_cast<const float4*>(&wl[t0 * HIDDEN + c]);
            float4 w1 = *reinterpret_cast<const float4*>(&wl[t1 * HIDDEN + c]);
            float4 w2 = *reinterpret_cast<const float4*>(&wl[t2 * HIDDEN + c]);
            float4 w3 = *reinterpret_cast<const float4*>(&wl[t3 * HIDDEN + c]);
            a0.x += h0.x * w0.x; a0.y += h0.y * w0.y; a0.z += h0.z * w0.z; a0.w += h0.w * w0.w;
            a1.x += h1.x * w1.x; a1.y += h1.y * w1.y; a1.z += h1.z * w1.z; a1.w += h1.w * w1.w;
            a2.x += h2.x * w2.x; a2.y += h2.y * w2.y; a2.z += h2.z * w2.z; a2.w += h2.w * w2.w;
            a3.x += h3.x * w3.x; a3.y += h3.y * w3.y; a3.z += h3.z * w3.z; a3.w += h3.w * w3.w;
        }
    }
    for (; e < end; ++e) {
        int e0 = sorted[e];
        int s0 = esrc[e0];
        int t0 = etype[e0];
        if (act) {
            const float* p0 = (s0 < NUM_ENT) ? ent + (size_t)s0 * HIDDEN : attr + (size_t)(s0 - NUM_ENT) * HIDDEN;
            float4 h0 = *reinterpret_cast<const float4*>(p0 + c);
            float4 w0 = *reinterpret_cast<const float4*>(&wl[t0 * HIDDEN + c]);
            a0.x += h0.x * w0.x; a0.y += h0.y * w0.y; a0.z += h0.z * w0.z; a0.w += h0.w * w0.w;
        }
    }

    if (act) {
        float4 acc = make_float4(a0.x + a1.x + a2.x + a3.x,
                                 a0.y + a1.y + a2.y + a3.y,
                                 a0.z + a1.z + a2.z + a3.z,
                                 a0.w + a1.w + a2.w + a3.w);
        *reinterpret_cast<float4*>(agg + (size_t)n * HIDDEN + c) = acc;
        float nm = norm[n];
        float v0 = acc.x * nm, v1 = acc.y * nm, v2 = acc.z * nm, v3 = acc.w * nm;
        v0 = (v0 >= 0.f) ? v0 : RRELU_SLOPE * v0;
        v1 = (v1 >= 0.f) ? v1 : RRELU_SLOPE * v1;
        v2 = (v2 >= 0.f) ? v2 : RRELU_SLOPE * v2;
        v3 = (v3 >= 0.f) ? v3 : RRELU_SLOPE * v3;
        bf16 t4[4] = {__float2bfloat16(v0), __float2bfloat16(v1),
                      __float2bfloat16(v2), __float2bfloat16(v3)};
        *reinterpret_cast<uint2*>(S + (size_t)n * KPAD + lane * 4) =
            *reinterpret_cast<uint2*>(t4);
    } else if (lane < KPAD / 4) {               // K-pad 200..223 -> zero
        bf16 z4[4] = {};
        *reinterpret_cast<uint2*>(S + (size_t)n * KPAD + lane * 4) =
            *reinterpret_cast<uint2*>(z4);
    }
}

// ---------------------------------------------------------------------------
// Y[m][n] = relu( x[m] . dec_W[n] + dec_b[n] )  as bf16 padded to KPAD.
// ---------------------------------------------------------------------------
__global__ void k_build_Y(const float* __restrict__ agg, const float* __restrict__ norm,
                          const float* __restrict__ rel_emb, const float* __restrict__ time_emb,
                          const float* __restrict__ dec_W, const float* __restrict__ dec_b,
                          const int* __restrict__ batch, bf16* __restrict__ Y) {
    __shared__ float xs[16][405];               // stride 405: odd vs 32 banks, conflict-free
    int t = threadIdx.x;
    int blk = blockIdx.x;
    for (int idx = t; idx < 16 * XDIM; idx += 256) {
        int r = idx / XDIM, c = idx - r * XDIM;
        int m = blk * 16 + r;
        float v;
        if (c < HIDDEN) {
            int e = batch[m * 4 + 0];
            float h = agg[(size_t)e * HIDDEN + c] * norm[e];
            h = (h >= 0.f) ? h : RRELU_SLOPE * h;
            v = tanhf(h);
        } else if (c < 2 * HIDDEN) {
            int rl = batch[m * 4 + 1];
            v = rel_emb[(size_t)rl * HIDDEN + (c - HIDDEN)];
        } else {
            int traw = batch[m * 4 + 3];
            v = time_emb[traw / 24];
        }
        xs[r][c] = v;
    }
    __syncthreads();
    int r = t & 15;                             // batch row within block
    int g = t >> 4;                             // output-column group
    int m = blk * 16 + r;
    for (int n = g; n < KPAD; n += 16) {
        float acc = 0.f;
        if (n < HIDDEN) {
            acc = dec_b[n];
            const float* wrow = dec_W + (size_t)n * XDIM;
            for (int k = 0; k < XDIM; ++k)
                acc += xs[r][k] * wrow[k];
            acc = fmaxf(acc, 0.f);
        }
        Y[(size_t)m * KPAD + n] = __float2bfloat16(acc);
    }
}

// ---------------------------------------------------------------------------
// out[4096][30000] (f32) = Y(4096xK) . S^T(Kx30000), bf16 MFMA 16x16x32.
// 1D grid 7520 blocks with XCD-chunked swizzle: each XCD owns a contiguous
// chunk of ~30 N-tiles x all 32 M-tiles -> per-XCD L2 working set
// A(1.8MB) + B-chunk(1.7MB) < 4MB, M-tile iterates fastest.
// ---------------------------------------------------------------------------
__global__ __launch_bounds__(256) void k_gemm(const bf16* __restrict__ Yb,
                                              const bf16* __restrict__ Sb,
                                              float* __restrict__ out) {
    int bid = blockIdx.x;                   // 0..7519 (= 235*32)
    int xcd = bid & 7;
    int t   = (bid >> 3) + xcd * 940;       // 7520/8 = 940, bijective
    int ytile = t & 31;                     // M tile (fast)
    int xtile = t >> 5;                     // N tile (slow, chunked per XCD)

    int wid  = threadIdx.x >> 6;
    int lane = threadIdx.x & 63;
    int wm = wid >> 1, wn = wid & 1;
    int row0 = ytile * 128 + wm * 64;
    int col0 = xtile * 128 + wn * 64;
    int rsel = lane & 15;
    int koff = (lane >> 4) * 8;

    const short* Yp = reinterpret_cast<const short*>(Yb);
    const short* Sp = reinterpret_cast<const short*>(Sb);

    f32x4 acc[4][4] = {};
#pragma unroll
    for (int kt = 0; kt < 7; ++kt) {
        int kbase = kt * 32 + koff;
        bf16x8 a[4], b[4];
#pragma unroll
        for (int i = 0; i < 4; ++i)
            a[i] = *reinterpret_cast<const bf16x8*>(Yp + (size_t)(row0 + i * 16 + rsel) * KPAD + kbase);
#pragma unroll
        for (int j = 0; j < 4; ++j)
            b[j] = *reinterpret_cast<const bf16x8*>(Sp + (size_t)(col0 + j * 16 + rsel) * KPAD + kbase);
#pragma unroll
        for (int i = 0; i < 4; ++i)
#pragma unroll
            for (int j = 0; j < 4; ++j)
                acc[i][j] = __builtin_amdgcn_mfma_f32_16x16x32_bf16(a[i], b[j], acc[i][j], 0, 0, 0);
    }

    int crow = (lane >> 4) * 4;     // C/D layout: col=lane&15, row=(lane>>4)*4+r
    int ccol = lane & 15;
#pragma unroll
    for (int i = 0; i < 4; ++i)
#pragma unroll
        for (int j = 0; j < 4; ++j) {
            int col = col0 + j * 16 + ccol;
            if (col >= NUM_ENT) continue;
#pragma unroll
            for (int r = 0; r < 4; ++r) {
                int row = row0 + i * 16 + crow + r;
                out[(size_t)row * NUM_ENT + col] = acc[i][j][r];
            }
        }
}

// ---------------------------------------------------------------------------
extern "C" void kernel_launch(void* const* d_in, const int* in_sizes, int n_in,
                              void* d_out, int out_size, void* d_ws, size_t ws_size,
                              hipStream_t stream) {
    const float* ent_emb  = (const float*)d_in[0];
    const float* attr_emb = (const float*)d_in[1];
    const float* rel_emb  = (const float*)d_in[2];
    const float* time_emb = (const float*)d_in[3];
    const float* rgcn_w   = (const float*)d_in[4];
    const float* dec_W    = (const float*)d_in[5];
    const float* dec_b    = (const float*)d_in[6];
    const float* norm     = (const float*)d_in[7];
    const int*   esrc     = (const int*)d_in[8];
    const int*   edst     = (const int*)d_in[9];
    const int*   etype    = (const int*)d_in[10];
    const int*   batch    = (const int*)d_in[11];

    char* ws = (char*)d_ws;
    float* agg    = (float*)ws;                         // 24,000,000 B
    bf16*  S      = (bf16*)(ws + 24000000);             // 13,475,840 B
    bf16*  Y      = (bf16*)(ws + 37475840);             //  1,835,008 B
    int*   counts = (int*)(ws + 39310848);              //   120,064 B (30001 ints)
    int*   offs   = (int*)(ws + 39430912);              //   120,064 B (30001 ints)
    int*   cursor = (int*)(ws + 39550976);              //   120,064 B (30000 ints)
    int*   sorted = (int*)(ws + 39671040);              // 2,400,000 B (600000 ints)

    k_zero_i<<<(NUM_ENT + 1 + 255) / 256, 256, 0, stream>>>(counts, NUM_ENT + 1);
    k_hist  <<<(N_EDGES + 255) / 256, 256, 0, stream>>>(edst, counts);
    k_scan  <<<1, 1024, 0, stream>>>(counts, offs, cursor);
    k_place <<<(N_EDGES + 255) / 256, 256, 0, stream>>>(edst, cursor, sorted);
    k_aggregate<<<(NPAD + 3) / 4, 256, 0, stream>>>(ent_emb, attr_emb, rgcn_w, esrc, etype,
                                                    offs, sorted, norm, agg, S);
    k_build_Y<<<BATCH / 16, 256, 0, stream>>>(agg, norm, rel_emb, time_emb, dec_W, dec_b, batch, Y);

    k_gemm<<<7520, 256, 0, stream>>>(Y, S, (float*)d_out);
}